// Round 6
// baseline (631.447 us; speedup 1.0000x reference)
//
#include <hip/hip_runtime.h>

#define NN 64      // notes
#define NW 256     // words
#define NB 32      // batch
#define WD 128     // word dim
#define OCH 256    // conv out channels
#define HD 256     // GRU hidden
#define G3 768     // 3*H

typedef __attribute__((ext_vector_type(8))) __bf16 bf16x8;
typedef __attribute__((ext_vector_type(4))) __bf16 bf16x4;
typedef __attribute__((ext_vector_type(4))) float  f32x4;

__device__ __forceinline__ float sigm(float x){ return 1.f/(1.f + __expf(-x)); }
__device__ __forceinline__ float tanh_(float x){
  float xx = fminf(fmaxf(x, -15.f), 15.f);
  float e = __expf(-2.f*xx);
  return (1.f - e)/(1.f + e);
}
__device__ __forceinline__ bf16x8 pack8(f32x4 a, f32x4 b){
  bf16x8 v;
  v[0]=(__bf16)a[0]; v[1]=(__bf16)a[1]; v[2]=(__bf16)a[2]; v[3]=(__bf16)a[3];
  v[4]=(__bf16)b[0]; v[5]=(__bf16)b[1]; v[6]=(__bf16)b[2]; v[7]=(__bf16)b[3];
  return v;
}
__device__ __forceinline__ void gload_lds16(const void* g, void* l){
  __builtin_amdgcn_global_load_lds(
      (const __attribute__((address_space(1))) unsigned int*)g,
      (__attribute__((address_space(3))) unsigned int*)l, 16, 0, 0);
}

// ---------------------------------------------------------------------------
// K0: one-time dtype conversions: embed table f32->bf16, conv_w f32->bf16
// ---------------------------------------------------------------------------
#define EMB_ELEMS 6400000   // 50000*128
#define CW_ELEMS  98304     // 256*384
__global__ void k0_cvt(const float* __restrict__ emb, const float* __restrict__ cw,
                       __bf16* __restrict__ embb, __bf16* __restrict__ cwb)
{
  long e8 = ((long)blockIdx.x*256 + threadIdx.x)*8;
  if (e8 < EMB_ELEMS) {
    f32x4 a = *(const f32x4*)(emb + e8); f32x4 b = *(const f32x4*)(emb + e8 + 4);
    *(bf16x8*)(embb + e8) = pack8(a, b);
  } else if (e8 < EMB_ELEMS + CW_ELEMS) {
    long o = e8 - EMB_ELEMS;
    f32x4 a = *(const f32x4*)(cw + o); f32x4 b = *(const f32x4*)(cw + o + 4);
    *(bf16x8*)(cwb + o) = pack8(a, b);
  }
}

// ---------------------------------------------------------------------------
// K1: embedding gather + conv(3x128, pad 2) + tanh + maxpool over words.
// ---------------------------------------------------------------------------
__global__ __launch_bounds__(512, 2) void k1_conv(
    const int* __restrict__ mb, const __bf16* __restrict__ embb,
    const __bf16* __restrict__ cwb, const float* __restrict__ cb,
    __bf16* __restrict__ feat)
{
  __shared__ int tok[NW];
  __shared__ __bf16 A[274*128];   // rows = word+2, 256B/row, swizzled 16B chunks
  const int blk = blockIdx.x, n = blk >> 5, b = blk & 31;
  const int t = threadIdx.x, wv = t >> 6, l = t & 63;
  const int lo = l & 15, hi = l >> 4;
  if (t < NW) tok[t] = mb[(n*NW + t)*NB + b];
  if (t < 288) {                   // zero rows 0,1 and 258..273 (padding)
    int rr = t >> 4, c = t & 15;
    int row = (rr < 2) ? rr : (256 + rr);
    f32x4 z = {0.f,0.f,0.f,0.f};
    *(f32x4*)((char*)A + row*256 + c*16) = z;
  }
  __syncthreads();
  #pragma unroll
  for (int rr = 0; rr < 8; ++rr) {  // DMA 4 rows per inst; lane: row=hi, chunk=lo
    const int w = wv*32 + rr*4 + hi;
    const int row = w + 2;
    const __bf16* src = embb + (long)tok[w]*WD + ((lo ^ (row & 7)) << 3);
    gload_lds16(src, &A[(wv*32 + rr*4 + 2)*128]);
  }
  __syncthreads();
  const int ocb = wv*32;
  bf16x8 B[2][12];                 // conv_w fragments: k = kw*128 + d
  #pragma unroll
  for (int nt = 0; nt < 2; ++nt) {
    int oc = ocb + nt*16 + lo;
    #pragma unroll
    for (int kf = 0; kf < 12; ++kf)
      B[nt][kf] = *(const bf16x8*)(cwb + oc*384 + kf*32 + hi*8);
  }
  f32x4 mx0 = {-3e38f,-3e38f,-3e38f,-3e38f}, mx1 = mx0;
  for (int mt = 0; mt < 17; ++mt) {      // 17 tiles of 16 output positions
    bf16x8 Af[12];
    const int lrow = mt*16 + lo;
    #pragma unroll
    for (int kf = 0; kf < 12; ++kf) {
      int prow = lrow + (kf >> 2);       // + kw
      int ch = (kf & 3)*4 + hi;
      Af[kf] = *(const bf16x8*)((char*)A + prow*256 + ((ch ^ (prow & 7)) << 4));
    }
    f32x4 a0 = {0,0,0,0}, a1 = {0,0,0,0};
    #pragma unroll
    for (int kf = 0; kf < 12; ++kf) {
      a0 = __builtin_amdgcn_mfma_f32_16x16x32_bf16(Af[kf], B[0][kf], a0, 0,0,0);
      a1 = __builtin_amdgcn_mfma_f32_16x16x32_bf16(Af[kf], B[1][kf], a1, 0,0,0);
    }
    const int rbase = mt*16 + hi*4;
    #pragma unroll
    for (int r = 0; r < 4; ++r) {
      if (rbase + r < 258) {             // valid conv positions only
        mx0[r] = fmaxf(mx0[r], a0[r]);
        mx1[r] = fmaxf(mx1[r], a1[r]);
      }
    }
  }
  float v0 = fmaxf(fmaxf(mx0[0], mx0[1]), fmaxf(mx0[2], mx0[3]));
  float v1 = fmaxf(fmaxf(mx1[0], mx1[1]), fmaxf(mx1[2], mx1[3]));
  v0 = fmaxf(v0, __shfl_xor(v0, 16)); v0 = fmaxf(v0, __shfl_xor(v0, 32));
  v1 = fmaxf(v1, __shfl_xor(v1, 16)); v1 = fmaxf(v1, __shfl_xor(v1, 32));
  if (l < 16) {                          // max(tanh(y+b)) == tanh(max(y)+b)
    const int m = n*NB + b;
    feat[m*OCH + ocb + l]      = (__bf16)tanh_(v0 + cb[ocb + l]);
    feat[m*OCH + ocb + 16 + l] = (__bf16)tanh_(v1 + cb[ocb + 16 + l]);
  }
}

// ---------------------------------------------------------------------------
// K2: gi = feat @ w_ih^T + b_ih (+ b_hh for r,z gates), both directions.
// Output layout for K3 DMA: gi_t[dir][note][bhalf][j=0..767][b16=0..15] f32
// ---------------------------------------------------------------------------
__global__ __launch_bounds__(256, 2) void k2_gi(
    const __bf16* __restrict__ feat,
    const float* __restrict__ wihf, const float* __restrict__ bihf, const float* __restrict__ bhhf,
    const float* __restrict__ wihb, const float* __restrict__ bihb, const float* __restrict__ bhhb,
    float* __restrict__ gi_t)
{
  const int bid = blockIdx.x;
  const int mblk = bid & 31, cblk = bid >> 5;     // cblk 0..23
  const int dir = (cblk >= 12) ? 1 : 0;
  const int jb = (cblk - dir*12)*64;
  const float* wih = dir ? wihb : wihf;
  const float* bih = dir ? bihb : bihf;
  const float* bhh = dir ? bhhb : bhhf;
  const int t = threadIdx.x, wv = t >> 6, l = t & 63;
  const int lo = l & 15, hi = l >> 4;
  const int mbase = mblk*64 + wv*16;
  bf16x8 Af[8];
  #pragma unroll
  for (int kf = 0; kf < 8; ++kf)
    Af[kf] = *(const bf16x8*)(feat + (mbase + lo)*HD + kf*32 + hi*8);
  bf16x8 Bf[4][8];
  #pragma unroll
  for (int nt = 0; nt < 4; ++nt) {
    int j = jb + nt*16 + lo;
    #pragma unroll
    for (int kf = 0; kf < 8; ++kf) {
      const float* src = wih + j*HD + kf*32 + hi*8;
      Bf[nt][kf] = pack8(*(const f32x4*)src, *(const f32x4*)(src + 4));
    }
  }
  f32x4 acc[4];
  #pragma unroll
  for (int nt = 0; nt < 4; ++nt) { f32x4 z = {0,0,0,0}; acc[nt] = z; }
  #pragma unroll
  for (int kf = 0; kf < 8; ++kf)
    #pragma unroll
    for (int nt = 0; nt < 4; ++nt)
      acc[nt] = __builtin_amdgcn_mfma_f32_16x16x32_bf16(Af[kf], Bf[nt][kf], acc[nt], 0,0,0);
  #pragma unroll
  for (int nt = 0; nt < 4; ++nt) {
    int j = jb + nt*16 + lo;
    float bias = bih[j] + (j < 512 ? bhh[j] : 0.f);
    #pragma unroll
    for (int r = 0; r < 4; ++r) {
      int m = mbase + hi*4 + r;
      int note = m >> 5, bb = m & 31;
      gi_t[((((long)dir*NN + note)*2 + (bb >> 4))*G3 + j)*16 + (bb & 15)] = acc[nt][r] + bias;
    }
  }
}

// ---------------------------------------------------------------------------
// K3: persistent GRU. grid=4 (dir x batch-half), 8 waves of 512 threads.
// Wave wv owns 96 cols: {g*256 + wv*32 + q*16 + lo | g=0..2, q=0..1} -> r/z/n
// in same lane => register-only gate math. Weights Bf = 192 VGPR.
// amdgpu_waves_per_eu(2,2): LDS (112KB) already limits to 1 block/CU = 2
// waves/SIMD, so tell the allocator its real budget is 256 VGPR (R5 failure:
// heuristic targeted 128 and spilled the weights to scratch).
// gi: f32, DMA'd to LDS (double buffer) one step ahead via global_load_lds.
// ---------------------------------------------------------------------------
__global__ __launch_bounds__(512)
__attribute__((amdgpu_waves_per_eu(2, 2)))
void k3_gru(
    const float* __restrict__ gi_t,
    const float* __restrict__ whhf, const float* __restrict__ bhhf,
    const float* __restrict__ whhb, const float* __restrict__ bhhb,
    const float* __restrict__ hid,
    float* __restrict__ out)
{
  const int blk = blockIdx.x;
  const int dir = blk >> 1, mtb = blk & 1;
  const float* whh = dir ? whhb : whhf;
  const float* bhh = dir ? bhhb : bhhf;
  const int t = threadIdx.x, wv = t >> 6, l = t & 63;
  const int lo = l & 15, hi = l >> 4;
  __shared__ __bf16 hb[2][16*256];    // 8 KB each, swizzled 16B chunks
  __shared__ float  gib[2][G3*16];    // 48 KB each: [j][b16]

  bf16x8 Bf[3][2][8];                 // [gate][q][kf] = 192 VGPR
  #pragma unroll
  for (int g = 0; g < 3; ++g)
    #pragma unroll
    for (int q = 0; q < 2; ++q) {
      const int col = g*256 + wv*32 + q*16 + lo;
      #pragma unroll
      for (int kf = 0; kf < 8; ++kf) {
        // volatile: loads are not sinkable/rematerializable -> values must
        // stay live in registers for the whole kernel.
        const volatile f32x4* src = (const volatile f32x4*)(whh + col*HD + kf*32 + hi*8);
        f32x4 a = src[0], b = src[1];
        Bf[g][q][kf] = pack8(a, b);
      }
    }
  const float bnh0 = bhh[512 + wv*32 + lo];
  const float bnh1 = bhh[512 + wv*32 + 16 + lo];

  f32x4 h[2];                         // h[q][r]: m=hi*4+r, j=wv*32+q*16+lo
  #pragma unroll
  for (int q = 0; q < 2; ++q)
    #pragma unroll
    for (int r = 0; r < 4; ++r)
      h[q][r] = hid[dir*(NB*HD) + (mtb*16 + hi*4 + r)*HD + wv*32 + q*16 + lo];

  #pragma unroll
  for (int q = 0; q < 2; ++q) {
    const int j = wv*32 + q*16 + lo;
    #pragma unroll
    for (int r = 0; r < 4; ++r) {
      const int row = hi*4 + r;
      *(__bf16*)((char*)&hb[0][0] + row*512 + (((j >> 3) ^ (row & 7)) << 4) + (j & 7)*2)
          = (__bf16)h[q][r];
    }
  }

  // prologue: DMA gi for step 0 into gib[0]
  const long gtile = ((long)(dir*NN + (dir ? 63 : 0))*2 + mtb)*(G3*16);
  #pragma unroll
  for (int p = 0; p < 6; ++p) {
    const int c = (p*8 + wv)*256;
    gload_lds16(gi_t + gtile + c + l*4, &gib[0][c]);
  }
  __syncthreads();                    // drains DMA + hb writes

  int cur = 0;
  for (int st = 0; st < 64; ++st) {
    const int note = dir ? 63 - st : st;
    // prefetch next step's gi into gib[cur^1] (hidden under this step's MFMA)
    if (st < 63) {
      const int nnote = dir ? 62 - st : st + 1;
      const long gt2 = ((long)(dir*NN + nnote)*2 + mtb)*(G3*16);
      #pragma unroll
      for (int p = 0; p < 6; ++p) {
        const int c = (p*8 + wv)*256;
        gload_lds16(gi_t + gt2 + c + l*4, &gib[cur ^ 1][c]);
      }
    }
    // MFMA: gh for this wave's 96 cols
    f32x4 acc[3][2];
    #pragma unroll
    for (int g = 0; g < 3; ++g)
      #pragma unroll
      for (int q = 0; q < 2; ++q) { f32x4 z = {0,0,0,0}; acc[g][q] = z; }
    const char* hbc = (const char*)&hb[cur][0];
    #pragma unroll
    for (int kf = 0; kf < 8; ++kf) {
      const int ch = kf*4 + hi;
      bf16x8 Afr = *(const bf16x8*)(hbc + lo*512 + ((ch ^ (lo & 7)) << 4));
      #pragma unroll
      for (int g = 0; g < 3; ++g)
        #pragma unroll
        for (int q = 0; q < 2; ++q)
          acc[g][q] = __builtin_amdgcn_mfma_f32_16x16x32_bf16(Afr, Bf[g][q][kf], acc[g][q], 0,0,0);
    }
    // gates (register-only) + h update
    char* hbn = (char*)&hb[cur ^ 1][0];
    const float* gcur = &gib[cur][0];
    #pragma unroll
    for (int q = 0; q < 2; ++q) {
      const int jH = wv*32 + q*16 + lo;
      f32x4 ir  = *(const f32x4*)(gcur + (jH        )*16 + hi*4);
      f32x4 iz  = *(const f32x4*)(gcur + (jH + 256  )*16 + hi*4);
      f32x4 in_ = *(const f32x4*)(gcur + (jH + 512  )*16 + hi*4);
      const float bn = q ? bnh1 : bnh0;
      #pragma unroll
      for (int r = 0; r < 4; ++r) {
        float rr = sigm(ir[r] + acc[0][q][r]);
        float zz = sigm(iz[r] + acc[1][q][r]);
        float nn = tanh_(in_[r] + rr*(acc[2][q][r] + bn));
        float hv = (1.f - zz)*nn + zz*h[q][r];
        h[q][r] = hv;
        const int row = hi*4 + r;
        *(__bf16*)(hbn + row*512 + (((jH >> 3) ^ (row & 7)) << 4) + (jH & 7)*2) = (__bf16)hv;
        out[(long)(note*NB + mtb*16 + row)*512 + dir*HD + jH] = hv;
      }
    }
    // counted drain: DMA for st+1 (6 oldest of <=14 outstanding) must land;
    // the 8 out-stores may stay in flight.
    asm volatile("s_waitcnt vmcnt(8) lgkmcnt(0)\n\ts_barrier" ::: "memory");
    cur ^= 1;
  }
}

// ---------------------------------------------------------------------------
// K4pre: transpose W_note (d,e) -> Wt (e,d) bf16
// ---------------------------------------------------------------------------
__global__ void k4pre(const float* __restrict__ Wn, __bf16* __restrict__ Wt){
  int idx = blockIdx.x*256 + threadIdx.x;
  int e = idx >> 9, d = idx & 511;
  Wt[e*512 + d] = (__bf16)Wn[d*512 + e];
}

// ---------------------------------------------------------------------------
// K4a: attn[m] = sum_e tanh(out_note[m,:] @ W_note[:,e] + bias[e]) * proj[e]
// ---------------------------------------------------------------------------
__global__ __launch_bounds__(256, 2) void k4a(
    const float* __restrict__ onf, const __bf16* __restrict__ Wt,
    const float* __restrict__ bn, const float* __restrict__ pj,
    float* __restrict__ attn)
{
  const int mbase = blockIdx.x*16;
  const int t = threadIdx.x, wv = t >> 6, l = t & 63;
  bf16x8 Af[16];
  #pragma unroll
  for (int kf = 0; kf < 16; ++kf) {
    const float* src = onf + (mbase + (l & 15))*512 + kf*32 + (l >> 4)*8;
    Af[kf] = pack8(*(const f32x4*)src, *(const f32x4*)(src + 4));
  }
  float aa0=0, aa1=0, aa2=0, aa3=0;
  #pragma unroll 1
  for (int ntl = 0; ntl < 8; ++ntl) {
    const int e = wv*128 + ntl*16 + (l & 15);
    const float be = bn[e], pe = pj[e];
    f32x4 acc = {0,0,0,0};
    #pragma unroll
    for (int kf = 0; kf < 16; ++kf) {
      bf16x8 Bfr = *(const bf16x8*)(Wt + e*512 + kf*32 + (l >> 4)*8);
      acc = __builtin_amdgcn_mfma_f32_16x16x32_bf16(Af[kf], Bfr, acc, 0,0,0);
    }
    aa0 += tanh_(acc[0] + be)*pe;
    aa1 += tanh_(acc[1] + be)*pe;
    aa2 += tanh_(acc[2] + be)*pe;
    aa3 += tanh_(acc[3] + be)*pe;
  }
  #pragma unroll
  for (int msk = 8; msk >= 1; msk >>= 1) {
    aa0 += __shfl_xor(aa0, msk); aa1 += __shfl_xor(aa1, msk);
    aa2 += __shfl_xor(aa2, msk); aa3 += __shfl_xor(aa3, msk);
  }
  __shared__ float part[4][16];
  if ((l & 15) == 0) {
    int rb = (l >> 4)*4;
    part[wv][rb+0]=aa0; part[wv][rb+1]=aa1; part[wv][rb+2]=aa2; part[wv][rb+3]=aa3;
  }
  __syncthreads();
  if (t < 16) attn[mbase + t] = part[0][t] + part[1][t] + part[2][t] + part[3][t];
}

// ---------------------------------------------------------------------------
// K4b: per-batch softmax over notes + attention vector + final linear
// ---------------------------------------------------------------------------
__global__ __launch_bounds__(512) void k4b(
    const float* __restrict__ attn, const float* __restrict__ lw, const float* __restrict__ lb,
    float* __restrict__ out)
{
  const int b = blockIdx.x, t = threadIdx.x;
  __shared__ float wl[64];
  __shared__ float vl[512];
  if (t < 64) {
    float a = attn[t*NB + b];
    float mx = a;
    #pragma unroll
    for (int msk = 32; msk >= 1; msk >>= 1) mx = fmaxf(mx, __shfl_xor(mx, msk));
    float ex = __expf(a - mx);
    float s = ex;
    #pragma unroll
    for (int msk = 32; msk >= 1; msk >>= 1) s += __shfl_xor(s, msk);
    float w = ex / s;
    out[1048576 + b*64 + t] = w;   // note_attn_norm [B,N]
    wl[t] = w;
  }
  __syncthreads();
  {
    float acc = 0.f;
    #pragma unroll 1
    for (int n = 0; n < 64; ++n) acc += wl[n]*out[(n*NB + b)*512 + t];
    out[1050624 + b*512 + t] = acc; // note_attn_vectors [B,2H]
    vl[t] = acc;
  }
  __syncthreads();
  if (t < 128) {
    int c = t >> 6, ln = t & 63;
    float p = 0.f;
    for (int d = ln; d < 512; d += 64) p += vl[d]*lw[c*512 + d];
    #pragma unroll
    for (int msk = 32; msk >= 1; msk >>= 1) p += __shfl_xor(p, msk);
    if (ln == 0) out[1067008 + b*2 + c] = p + lb[c]; // final_map [B,2]
  }
}

// ---------------------------------------------------------------------------
extern "C" void kernel_launch(void* const* d_in, const int* in_sizes, int n_in,
                              void* d_out, int out_size, void* d_ws, size_t ws_size,
                              hipStream_t stream) {
  const int*   mb   = (const int*)d_in[0];
  const float* hid  = (const float*)d_in[1];
  const float* emb  = (const float*)d_in[2];
  const float* cw   = (const float*)d_in[3];
  const float* cb   = (const float*)d_in[4];
  const float* wihf = (const float*)d_in[5];
  const float* whhf = (const float*)d_in[6];
  const float* bihf = (const float*)d_in[7];
  const float* bhhf = (const float*)d_in[8];
  const float* wihb = (const float*)d_in[9];
  const float* whhb = (const float*)d_in[10];
  const float* bihb = (const float*)d_in[11];
  const float* bhhb = (const float*)d_in[12];
  const float* Wn   = (const float*)d_in[13];
  const float* bnote= (const float*)d_in[14];
  const float* pj   = (const float*)d_in[15];
  const float* lw   = (const float*)d_in[16];
  const float* lb   = (const float*)d_in[17];
  float* out = (float*)d_out;
  char* ws = (char*)d_ws;
  // layout (embb overlaps gi_t: embb dead after k1, gi_t born in k2)
  __bf16* feat = (__bf16*)ws;                       // 1 MB     [2048 x 256]
  __bf16* embb = (__bf16*)(ws + 1048576);           // 12.8 MB  [50000 x 128]
  float*  gi_t = (float*)(ws + 1048576);            // 12.58 MB [2][64][2][768][16]
  float*  attn = (float*)(ws + 13848576);           // 8 KB     [2048]
  __bf16* Wt   = (__bf16*)(ws + 13856768);          // 512 KB   [512 x 512]
  __bf16* cwb  = (__bf16*)(ws + 14380800);          // 192 KB   [256 x 384]

  k0_cvt<<<3173, 256, 0, stream>>>(emb, cw, embb, cwb);
  k1_conv<<<2048, 512, 0, stream>>>(mb, embb, cwb, cb, feat);
  k2_gi<<<768, 256, 0, stream>>>(feat, wihf, bihf, bhhf, wihb, bihb, bhhb, gi_t);
  k4pre<<<1024, 256, 0, stream>>>(Wn, Wt);
  k3_gru<<<4, 512, 0, stream>>>(gi_t, whhf, bhhf, whhb, bhhb, hid, out);
  k4a<<<128, 256, 0, stream>>>(out, Wt, bnote, pj, attn);
  k4b<<<32, 512, 0, stream>>>(attn, lw, lb, out);
}

// Round 9
// 606.936 us; speedup vs baseline: 1.0404x; 1.0404x over previous
//
#include <hip/hip_runtime.h>

#define NN 64      // notes
#define NW 256     // words
#define NB 32      // batch
#define WD 128     // word dim
#define OCH 256    // conv out channels
#define HD 256     // GRU hidden
#define G3 768     // 3*H

typedef __attribute__((ext_vector_type(8))) __bf16 bf16x8;
typedef __attribute__((ext_vector_type(4))) __bf16 bf16x4;
typedef __attribute__((ext_vector_type(4))) float  f32x4;

__device__ __forceinline__ float sigm(float x){ return 1.f/(1.f + __expf(-x)); }
__device__ __forceinline__ float tanh_(float x){
  float xx = fminf(fmaxf(x, -15.f), 15.f);
  float e = __expf(-2.f*xx);
  return (1.f - e)/(1.f + e);
}
__device__ __forceinline__ bf16x8 pack8(f32x4 a, f32x4 b){
  bf16x8 v;
  v[0]=(__bf16)a[0]; v[1]=(__bf16)a[1]; v[2]=(__bf16)a[2]; v[3]=(__bf16)a[3];
  v[4]=(__bf16)b[0]; v[5]=(__bf16)b[1]; v[6]=(__bf16)b[2]; v[7]=(__bf16)b[3];
  return v;
}
__device__ __forceinline__ void gload_lds16(const void* g, void* l){
  __builtin_amdgcn_global_load_lds(
      (const __attribute__((address_space(1))) unsigned int*)g,
      (__attribute__((address_space(3))) unsigned int*)l, 16, 0, 0);
}

// ---------------------------------------------------------------------------
// K0: one-time dtype conversions: embed table f32->bf16, conv_w f32->bf16
// ---------------------------------------------------------------------------
#define EMB_ELEMS 6400000   // 50000*128
#define CW_ELEMS  98304     // 256*384
__global__ void k0_cvt(const float* __restrict__ emb, const float* __restrict__ cw,
                       __bf16* __restrict__ embb, __bf16* __restrict__ cwb)
{
  long e8 = ((long)blockIdx.x*256 + threadIdx.x)*8;
  if (e8 < EMB_ELEMS) {
    f32x4 a = *(const f32x4*)(emb + e8); f32x4 b = *(const f32x4*)(emb + e8 + 4);
    *(bf16x8*)(embb + e8) = pack8(a, b);
  } else if (e8 < EMB_ELEMS + CW_ELEMS) {
    long o = e8 - EMB_ELEMS;
    f32x4 a = *(const f32x4*)(cw + o); f32x4 b = *(const f32x4*)(cw + o + 4);
    *(bf16x8*)(cwb + o) = pack8(a, b);
  }
}

// ---------------------------------------------------------------------------
// K1: embedding gather + conv(3x128, pad 2) + tanh + maxpool over words.
// ---------------------------------------------------------------------------
__global__ __launch_bounds__(512, 2) void k1_conv(
    const int* __restrict__ mb, const __bf16* __restrict__ embb,
    const __bf16* __restrict__ cwb, const float* __restrict__ cb,
    __bf16* __restrict__ feat)
{
  __shared__ int tok[NW];
  __shared__ __bf16 A[274*128];   // rows = word+2, 256B/row, swizzled 16B chunks
  const int blk = blockIdx.x, n = blk >> 5, b = blk & 31;
  const int t = threadIdx.x, wv = t >> 6, l = t & 63;
  const int lo = l & 15, hi = l >> 4;
  if (t < NW) tok[t] = mb[(n*NW + t)*NB + b];
  if (t < 288) {                   // zero rows 0,1 and 258..273 (padding)
    int rr = t >> 4, c = t & 15;
    int row = (rr < 2) ? rr : (256 + rr);
    f32x4 z = {0.f,0.f,0.f,0.f};
    *(f32x4*)((char*)A + row*256 + c*16) = z;
  }
  __syncthreads();
  #pragma unroll
  for (int rr = 0; rr < 8; ++rr) {  // DMA 4 rows per inst; lane: row=hi, chunk=lo
    const int w = wv*32 + rr*4 + hi;
    const int row = w + 2;
    const __bf16* src = embb + (long)tok[w]*WD + ((lo ^ (row & 7)) << 3);
    gload_lds16(src, &A[(wv*32 + rr*4 + 2)*128]);
  }
  __syncthreads();
  const int ocb = wv*32;
  bf16x8 B[2][12];                 // conv_w fragments: k = kw*128 + d
  #pragma unroll
  for (int nt = 0; nt < 2; ++nt) {
    int oc = ocb + nt*16 + lo;
    #pragma unroll
    for (int kf = 0; kf < 12; ++kf)
      B[nt][kf] = *(const bf16x8*)(cwb + oc*384 + kf*32 + hi*8);
  }
  f32x4 mx0 = {-3e38f,-3e38f,-3e38f,-3e38f}, mx1 = mx0;
  for (int mt = 0; mt < 17; ++mt) {      // 17 tiles of 16 output positions
    bf16x8 Af[12];
    const int lrow = mt*16 + lo;
    #pragma unroll
    for (int kf = 0; kf < 12; ++kf) {
      int prow = lrow + (kf >> 2);       // + kw
      int ch = (kf & 3)*4 + hi;
      Af[kf] = *(const bf16x8*)((char*)A + prow*256 + ((ch ^ (prow & 7)) << 4));
    }
    f32x4 a0 = {0,0,0,0}, a1 = {0,0,0,0};
    #pragma unroll
    for (int kf = 0; kf < 12; ++kf) {
      a0 = __builtin_amdgcn_mfma_f32_16x16x32_bf16(Af[kf], B[0][kf], a0, 0,0,0);
      a1 = __builtin_amdgcn_mfma_f32_16x16x32_bf16(Af[kf], B[1][kf], a1, 0,0,0);
    }
    const int rbase = mt*16 + hi*4;
    #pragma unroll
    for (int r = 0; r < 4; ++r) {
      if (rbase + r < 258) {             // valid conv positions only
        mx0[r] = fmaxf(mx0[r], a0[r]);
        mx1[r] = fmaxf(mx1[r], a1[r]);
      }
    }
  }
  float v0 = fmaxf(fmaxf(mx0[0], mx0[1]), fmaxf(mx0[2], mx0[3]));
  float v1 = fmaxf(fmaxf(mx1[0], mx1[1]), fmaxf(mx1[2], mx1[3]));
  v0 = fmaxf(v0, __shfl_xor(v0, 16)); v0 = fmaxf(v0, __shfl_xor(v0, 32));
  v1 = fmaxf(v1, __shfl_xor(v1, 16)); v1 = fmaxf(v1, __shfl_xor(v1, 32));
  if (l < 16) {                          // max(tanh(y+b)) == tanh(max(y)+b)
    const int m = n*NB + b;
    feat[m*OCH + ocb + l]      = (__bf16)tanh_(v0 + cb[ocb + l]);
    feat[m*OCH + ocb + 16 + l] = (__bf16)tanh_(v1 + cb[ocb + 16 + l]);
  }
}

// ---------------------------------------------------------------------------
// K2: gi = feat @ w_ih^T + b_ih (+ b_hh for r,z gates), both directions.
// Output BF16, layout for K3 DMA: gi_t[dir][note][bhalf][j=0..767][b16=0..15]
// ---------------------------------------------------------------------------
__global__ __launch_bounds__(256, 2) void k2_gi(
    const __bf16* __restrict__ feat,
    const float* __restrict__ wihf, const float* __restrict__ bihf, const float* __restrict__ bhhf,
    const float* __restrict__ wihb, const float* __restrict__ bihb, const float* __restrict__ bhhb,
    __bf16* __restrict__ gi_t)
{
  const int bid = blockIdx.x;
  const int mblk = bid & 31, cblk = bid >> 5;     // cblk 0..23
  const int dir = (cblk >= 12) ? 1 : 0;
  const int jb = (cblk - dir*12)*64;
  const float* wih = dir ? wihb : wihf;
  const float* bih = dir ? bihb : bihf;
  const float* bhh = dir ? bhhb : bhhf;
  const int t = threadIdx.x, wv = t >> 6, l = t & 63;
  const int lo = l & 15, hi = l >> 4;
  const int mbase = mblk*64 + wv*16;
  bf16x8 Af[8];
  #pragma unroll
  for (int kf = 0; kf < 8; ++kf)
    Af[kf] = *(const bf16x8*)(feat + (mbase + lo)*HD + kf*32 + hi*8);
  bf16x8 Bf[4][8];
  #pragma unroll
  for (int nt = 0; nt < 4; ++nt) {
    int j = jb + nt*16 + lo;
    #pragma unroll
    for (int kf = 0; kf < 8; ++kf) {
      const float* src = wih + j*HD + kf*32 + hi*8;
      Bf[nt][kf] = pack8(*(const f32x4*)src, *(const f32x4*)(src + 4));
    }
  }
  f32x4 acc[4];
  #pragma unroll
  for (int nt = 0; nt < 4; ++nt) { f32x4 z = {0,0,0,0}; acc[nt] = z; }
  #pragma unroll
  for (int kf = 0; kf < 8; ++kf)
    #pragma unroll
    for (int nt = 0; nt < 4; ++nt)
      acc[nt] = __builtin_amdgcn_mfma_f32_16x16x32_bf16(Af[kf], Bf[nt][kf], acc[nt], 0,0,0);
  #pragma unroll
  for (int nt = 0; nt < 4; ++nt) {
    int j = jb + nt*16 + lo;
    float bias = bih[j] + (j < 512 ? bhh[j] : 0.f);
    #pragma unroll
    for (int r = 0; r < 4; ++r) {
      int m = mbase + hi*4 + r;
      int note = m >> 5, bb = m & 31;
      gi_t[((((long)dir*NN + note)*2 + (bb >> 4))*G3 + j)*16 + (bb & 15)]
          = (__bf16)(acc[nt][r] + bias);
    }
  }
}

// ---------------------------------------------------------------------------
// K3: persistent GRU. grid=4 (dir x batch-half), 16 waves of 1024 threads.
// Wave wv owns hidden col j=wv*16+lo for ALL THREE gates (cols j, j+256,
// j+512) -> register-only gate math. Weights: 24 bf16x8 = 96 VGPR/lane --
// fits the hard 128-reg budget of a 1024-thread block (R5/R6 failure: 512
// threads need 192 weight regs, allocator granted 128 -> spill every step).
// gi: bf16, DMA'd to LDS (double buffer) one step ahead via global_load_lds.
// One barrier/step with counted vmcnt(4): the 2 prefetch DMAs are always
// drained (>=4 newer out-stores exist), out-stores stay in flight.
// ---------------------------------------------------------------------------
__global__ __launch_bounds__(1024) void k3_gru(
    const __bf16* __restrict__ gi_t,
    const float* __restrict__ whhf, const float* __restrict__ bhhf,
    const float* __restrict__ whhb, const float* __restrict__ bhhb,
    const float* __restrict__ hid,
    float* __restrict__ out)
{
  const int blk = blockIdx.x;
  const int dir = blk >> 1, mtb = blk & 1;
  const float* whh = dir ? whhb : whhf;
  const float* bhh = dir ? bhhb : bhhf;
  const int t = threadIdx.x, wv = t >> 6, l = t & 63;
  const int lo = l & 15, hi = l >> 4;
  __shared__ __bf16 hb[2][16*256];    // 8 KB each, swizzled 16B chunks
  __shared__ __bf16 gib[2][G3*16];    // 24 KB each: [j][b16] bf16

  const int jl = wv*16 + lo;          // this lane's hidden unit
  bf16x8 Bf[3][8];                    // [gate][kf] = 96 VGPR
  #pragma unroll
  for (int g = 0; g < 3; ++g) {
    const int col = g*256 + jl;
    #pragma unroll
    for (int kf = 0; kf < 8; ++kf) {
      const float* src = whh + col*HD + kf*32 + hi*8;
      Bf[g][kf] = pack8(*(const f32x4*)src, *(const f32x4*)(src + 4));
    }
  }
  const float bnh = bhh[512 + jl];

  float h[4];                         // rows m = hi*4+r (in batch-half), col jl
  #pragma unroll
  for (int r = 0; r < 4; ++r)
    h[r] = hid[dir*(NB*HD) + (mtb*16 + hi*4 + r)*HD + jl];
  #pragma unroll
  for (int r = 0; r < 4; ++r) {
    const int row = hi*4 + r;
    *(__bf16*)((char*)&hb[0][0] + row*512 + (((jl >> 3) ^ (row & 7)) << 4) + (jl & 7)*2)
        = (__bf16)h[r];
  }

  // prologue: DMA gi for step 0 into gib[0]  (24 KB = 24 wave-instructions)
  {
    const int note0 = dir ? 63 : 0;
    const __bf16* gt = gi_t + ((long)(dir*NN + note0)*2 + mtb)*(G3*16);
    gload_lds16(gt + wv*512 + l*8, &gib[0][wv*512]);
    if (wv < 8) gload_lds16(gt + (16 + wv)*512 + l*8, &gib[0][(16 + wv)*512]);
  }
  asm volatile("s_waitcnt vmcnt(0) lgkmcnt(0)\n\ts_barrier" ::: "memory");

  int cur = 0;
  for (int st = 0; st < 64; ++st) {
    const int note = dir ? 63 - st : st;
    // prefetch next step's gi into gib[cur^1] (hidden under this step's MFMA)
    if (st < 63) {
      const int nn2 = dir ? 62 - st : st + 1;
      const __bf16* gt = gi_t + ((long)(dir*NN + nn2)*2 + mtb)*(G3*16);
      gload_lds16(gt + wv*512 + l*8, &gib[cur ^ 1][wv*512]);
      if (wv < 8) gload_lds16(gt + (16 + wv)*512 + l*8, &gib[cur ^ 1][(16 + wv)*512]);
    }
    // MFMA: gh for cols {jl, jl+256, jl+512}
    f32x4 acc[3];
    #pragma unroll
    for (int g = 0; g < 3; ++g) { f32x4 z = {0,0,0,0}; acc[g] = z; }
    const char* hbc = (const char*)&hb[cur][0];
    #pragma unroll
    for (int kf = 0; kf < 8; ++kf) {
      const int ch = kf*4 + hi;
      bf16x8 Afr = *(const bf16x8*)(hbc + lo*512 + ((ch ^ (lo & 7)) << 4));
      #pragma unroll
      for (int g = 0; g < 3; ++g)
        acc[g] = __builtin_amdgcn_mfma_f32_16x16x32_bf16(Afr, Bf[g][kf], acc[g], 0,0,0);
    }
    // gates (register-only) + h update
    char* hbn = (char*)&hb[cur ^ 1][0];
    const char* gc = (const char*)&gib[cur][0];
    bf16x4 ur  = *(const bf16x4*)(gc + jl*32 + hi*8);           // gate r
    bf16x4 uz  = *(const bf16x4*)(gc + 8192  + jl*32 + hi*8);   // gate z
    bf16x4 un  = *(const bf16x4*)(gc + 16384 + jl*32 + hi*8);   // gate n
    #pragma unroll
    for (int r = 0; r < 4; ++r) {
      float rr = sigm((float)ur[r] + acc[0][r]);
      float zz = sigm((float)uz[r] + acc[1][r]);
      float nn = tanh_((float)un[r] + rr*(acc[2][r] + bnh));
      float hv = (1.f - zz)*nn + zz*h[r];
      h[r] = hv;
      const int row = hi*4 + r;
      *(__bf16*)(hbn + row*512 + (((jl >> 3) ^ (row & 7)) << 4) + (jl & 7)*2) = (__bf16)hv;
      out[(long)(note*NB + mtb*16 + row)*512 + dir*HD + jl] = hv;
    }
    // counted drain: the 2 (or 1) prefetch DMAs are the oldest VMEM ops and
    // >=4 newer ops (out-stores) exist -> vmcnt(4) drains DMAs, keeps stores
    // in flight, regardless of any compiler-inserted scratch ops in between.
    asm volatile("s_waitcnt vmcnt(4) lgkmcnt(0)\n\ts_barrier" ::: "memory");
    cur ^= 1;
  }
}

// ---------------------------------------------------------------------------
// K4pre: transpose W_note (d,e) -> Wt (e,d) bf16
// ---------------------------------------------------------------------------
__global__ void k4pre(const float* __restrict__ Wn, __bf16* __restrict__ Wt){
  int idx = blockIdx.x*256 + threadIdx.x;
  int e = idx >> 9, d = idx & 511;
  Wt[e*512 + d] = (__bf16)Wn[d*512 + e];
}

// ---------------------------------------------------------------------------
// K4a: attn[m] = sum_e tanh(out_note[m,:] @ W_note[:,e] + bias[e]) * proj[e]
// ---------------------------------------------------------------------------
__global__ __launch_bounds__(256, 2) void k4a(
    const float* __restrict__ onf, const __bf16* __restrict__ Wt,
    const float* __restrict__ bn, const float* __restrict__ pj,
    float* __restrict__ attn)
{
  const int mbase = blockIdx.x*16;
  const int t = threadIdx.x, wv = t >> 6, l = t & 63;
  bf16x8 Af[16];
  #pragma unroll
  for (int kf = 0; kf < 16; ++kf) {
    const float* src = onf + (mbase + (l & 15))*512 + kf*32 + (l >> 4)*8;
    Af[kf] = pack8(*(const f32x4*)src, *(const f32x4*)(src + 4));
  }
  float aa0=0, aa1=0, aa2=0, aa3=0;
  #pragma unroll 1
  for (int ntl = 0; ntl < 8; ++ntl) {
    const int e = wv*128 + ntl*16 + (l & 15);
    const float be = bn[e], pe = pj[e];
    f32x4 acc = {0,0,0,0};
    #pragma unroll
    for (int kf = 0; kf < 16; ++kf) {
      bf16x8 Bfr = *(const bf16x8*)(Wt + e*512 + kf*32 + (l >> 4)*8);
      acc = __builtin_amdgcn_mfma_f32_16x16x32_bf16(Af[kf], Bfr, acc, 0,0,0);
    }
    aa0 += tanh_(acc[0] + be)*pe;
    aa1 += tanh_(acc[1] + be)*pe;
    aa2 += tanh_(acc[2] + be)*pe;
    aa3 += tanh_(acc[3] + be)*pe;
  }
  #pragma unroll
  for (int msk = 8; msk >= 1; msk >>= 1) {
    aa0 += __shfl_xor(aa0, msk); aa1 += __shfl_xor(aa1, msk);
    aa2 += __shfl_xor(aa2, msk); aa3 += __shfl_xor(aa3, msk);
  }
  __shared__ float part[4][16];
  if ((l & 15) == 0) {
    int rb = (l >> 4)*4;
    part[wv][rb+0]=aa0; part[wv][rb+1]=aa1; part[wv][rb+2]=aa2; part[wv][rb+3]=aa3;
  }
  __syncthreads();
  if (t < 16) attn[mbase + t] = part[0][t] + part[1][t] + part[2][t] + part[3][t];
}

// ---------------------------------------------------------------------------
// K4b: per-batch softmax over notes + attention vector + final linear
// ---------------------------------------------------------------------------
__global__ __launch_bounds__(512) void k4b(
    const float* __restrict__ attn, const float* __restrict__ lw, const float* __restrict__ lb,
    float* __restrict__ out)
{
  const int b = blockIdx.x, t = threadIdx.x;
  __shared__ float wl[64];
  __shared__ float vl[512];
  if (t < 64) {
    float a = attn[t*NB + b];
    float mx = a;
    #pragma unroll
    for (int msk = 32; msk >= 1; msk >>= 1) mx = fmaxf(mx, __shfl_xor(mx, msk));
    float ex = __expf(a - mx);
    float s = ex;
    #pragma unroll
    for (int msk = 32; msk >= 1; msk >>= 1) s += __shfl_xor(s, msk);
    float w = ex / s;
    out[1048576 + b*64 + t] = w;   // note_attn_norm [B,N]
    wl[t] = w;
  }
  __syncthreads();
  {
    float acc = 0.f;
    #pragma unroll 1
    for (int n = 0; n < 64; ++n) acc += wl[n]*out[(n*NB + b)*512 + t];
    out[1050624 + b*512 + t] = acc; // note_attn_vectors [B,2H]
    vl[t] = acc;
  }
  __syncthreads();
  if (t < 128) {
    int c = t >> 6, ln = t & 63;
    float p = 0.f;
    for (int d = ln; d < 512; d += 64) p += vl[d]*lw[c*512 + d];
    #pragma unroll
    for (int msk = 32; msk >= 1; msk >>= 1) p += __shfl_xor(p, msk);
    if (ln == 0) out[1067008 + b*2 + c] = p + lb[c]; // final_map [B,2]
  }
}

// ---------------------------------------------------------------------------
extern "C" void kernel_launch(void* const* d_in, const int* in_sizes, int n_in,
                              void* d_out, int out_size, void* d_ws, size_t ws_size,
                              hipStream_t stream) {
  const int*   mb   = (const int*)d_in[0];
  const float* hid  = (const float*)d_in[1];
  const float* emb  = (const float*)d_in[2];
  const float* cw   = (const float*)d_in[3];
  const float* cb   = (const float*)d_in[4];
  const float* wihf = (const float*)d_in[5];
  const float* whhf = (const float*)d_in[6];
  const float* bihf = (const float*)d_in[7];
  const float* bhhf = (const float*)d_in[8];
  const float* wihb = (const float*)d_in[9];
  const float* whhb = (const float*)d_in[10];
  const float* bihb = (const float*)d_in[11];
  const float* bhhb = (const float*)d_in[12];
  const float* Wn   = (const float*)d_in[13];
  const float* bnote= (const float*)d_in[14];
  const float* pj   = (const float*)d_in[15];
  const float* lw   = (const float*)d_in[16];
  const float* lb   = (const float*)d_in[17];
  float* out = (float*)d_out;
  char* ws = (char*)d_ws;
  // layout (embb overlaps gi_t region: embb dead after k1, gi_t born in k2)
  __bf16* feat = (__bf16*)ws;                       // 1 MB     [2048 x 256]
  __bf16* embb = (__bf16*)(ws + 1048576);           // 12.8 MB  [50000 x 128]
  __bf16* gi_t = (__bf16*)(ws + 1048576);           // 6.29 MB  [2][64][2][768][16] bf16
  float*  attn = (float*)(ws + 13848576);           // 8 KB     [2048]
  __bf16* Wt   = (__bf16*)(ws + 13856768);          // 512 KB   [512 x 512]
  __bf16* cwb  = (__bf16*)(ws + 14380800);          // 192 KB   [256 x 384]

  k0_cvt<<<3173, 256, 0, stream>>>(emb, cw, embb, cwb);
  k1_conv<<<2048, 512, 0, stream>>>(mb, embb, cwb, cb, feat);
  k2_gi<<<768, 256, 0, stream>>>(feat, wihf, bihf, bhhf, wihb, bihb, bhhb, gi_t);
  k4pre<<<1024, 256, 0, stream>>>(Wn, Wt);
  k3_gru<<<4, 1024, 0, stream>>>(gi_t, whhf, bhhf, whhb, bhhb, hid, out);
  k4a<<<128, 256, 0, stream>>>(out, Wt, bnote, pj, attn);
  k4b<<<32, 512, 0, stream>>>(attn, lw, lb, out);
}

// Round 10
// 586.842 us; speedup vs baseline: 1.0760x; 1.0342x over previous
//
#include <hip/hip_runtime.h>

#define NN 64      // notes
#define NW 256     // words
#define NB 32      // batch
#define WD 128     // word dim
#define OCH 256    // conv out channels
#define HD 256     // GRU hidden
#define G3 768     // 3*H

typedef __attribute__((ext_vector_type(8))) __bf16 bf16x8;
typedef __attribute__((ext_vector_type(4))) __bf16 bf16x4;
typedef __attribute__((ext_vector_type(4))) float  f32x4;

__device__ __forceinline__ float sigm(float x){ return 1.f/(1.f + __expf(-x)); }
__device__ __forceinline__ float tanh_(float x){
  float xx = fminf(fmaxf(x, -15.f), 15.f);
  float e = __expf(-2.f*xx);
  return (1.f - e)/(1.f + e);
}
__device__ __forceinline__ bf16x8 pack8(f32x4 a, f32x4 b){
  bf16x8 v;
  v[0]=(__bf16)a[0]; v[1]=(__bf16)a[1]; v[2]=(__bf16)a[2]; v[3]=(__bf16)a[3];
  v[4]=(__bf16)b[0]; v[5]=(__bf16)b[1]; v[6]=(__bf16)b[2]; v[7]=(__bf16)b[3];
  return v;
}
__device__ __forceinline__ void gload_lds16(const void* g, void* l){
  __builtin_amdgcn_global_load_lds(
      (const __attribute__((address_space(1))) unsigned int*)g,
      (__attribute__((address_space(3))) unsigned int*)l, 16, 0, 0);
}

// ---------------------------------------------------------------------------
// K0: one-time dtype conversions: embed table f32->bf16, conv_w f32->bf16
// ---------------------------------------------------------------------------
#define EMB_ELEMS 6400000   // 50000*128
#define CW_ELEMS  98304     // 256*384
__global__ void k0_cvt(const float* __restrict__ emb, const float* __restrict__ cw,
                       __bf16* __restrict__ embb, __bf16* __restrict__ cwb)
{
  long e8 = ((long)blockIdx.x*256 + threadIdx.x)*8;
  if (e8 < EMB_ELEMS) {
    f32x4 a = *(const f32x4*)(emb + e8); f32x4 b = *(const f32x4*)(emb + e8 + 4);
    *(bf16x8*)(embb + e8) = pack8(a, b);
  } else if (e8 < EMB_ELEMS + CW_ELEMS) {
    long o = e8 - EMB_ELEMS;
    f32x4 a = *(const f32x4*)(cw + o); f32x4 b = *(const f32x4*)(cw + o + 4);
    *(bf16x8*)(cwb + o) = pack8(a, b);
  }
}

// ---------------------------------------------------------------------------
// K1: embedding gather + conv(3x128, pad 2) + tanh + maxpool over words.
// ---------------------------------------------------------------------------
__global__ __launch_bounds__(512, 2) void k1_conv(
    const int* __restrict__ mb, const __bf16* __restrict__ embb,
    const __bf16* __restrict__ cwb, const float* __restrict__ cb,
    __bf16* __restrict__ feat)
{
  __shared__ int tok[NW];
  __shared__ __bf16 A[274*128];   // rows = word+2, 256B/row, swizzled 16B chunks
  const int blk = blockIdx.x, n = blk >> 5, b = blk & 31;
  const int t = threadIdx.x, wv = t >> 6, l = t & 63;
  const int lo = l & 15, hi = l >> 4;
  if (t < NW) tok[t] = mb[(n*NW + t)*NB + b];
  if (t < 288) {                   // zero rows 0,1 and 258..273 (padding)
    int rr = t >> 4, c = t & 15;
    int row = (rr < 2) ? rr : (256 + rr);
    f32x4 z = {0.f,0.f,0.f,0.f};
    *(f32x4*)((char*)A + row*256 + c*16) = z;
  }
  __syncthreads();
  #pragma unroll
  for (int rr = 0; rr < 8; ++rr) {  // DMA 4 rows per inst; lane: row=hi, chunk=lo
    const int w = wv*32 + rr*4 + hi;
    const int row = w + 2;
    const __bf16* src = embb + (long)tok[w]*WD + ((lo ^ (row & 7)) << 3);
    gload_lds16(src, &A[(wv*32 + rr*4 + 2)*128]);
  }
  __syncthreads();
  const int ocb = wv*32;
  bf16x8 B[2][12];                 // conv_w fragments: k = kw*128 + d
  #pragma unroll
  for (int nt = 0; nt < 2; ++nt) {
    int oc = ocb + nt*16 + lo;
    #pragma unroll
    for (int kf = 0; kf < 12; ++kf)
      B[nt][kf] = *(const bf16x8*)(cwb + oc*384 + kf*32 + hi*8);
  }
  f32x4 mx0 = {-3e38f,-3e38f,-3e38f,-3e38f}, mx1 = mx0;
  for (int mt = 0; mt < 17; ++mt) {      // 17 tiles of 16 output positions
    bf16x8 Af[12];
    const int lrow = mt*16 + lo;
    #pragma unroll
    for (int kf = 0; kf < 12; ++kf) {
      int prow = lrow + (kf >> 2);       // + kw
      int ch = (kf & 3)*4 + hi;
      Af[kf] = *(const bf16x8*)((char*)A + prow*256 + ((ch ^ (prow & 7)) << 4));
    }
    f32x4 a0 = {0,0,0,0}, a1 = {0,0,0,0};
    #pragma unroll
    for (int kf = 0; kf < 12; ++kf) {
      a0 = __builtin_amdgcn_mfma_f32_16x16x32_bf16(Af[kf], B[0][kf], a0, 0,0,0);
      a1 = __builtin_amdgcn_mfma_f32_16x16x32_bf16(Af[kf], B[1][kf], a1, 0,0,0);
    }
    const int rbase = mt*16 + hi*4;
    #pragma unroll
    for (int r = 0; r < 4; ++r) {
      if (rbase + r < 258) {             // valid conv positions only
        mx0[r] = fmaxf(mx0[r], a0[r]);
        mx1[r] = fmaxf(mx1[r], a1[r]);
      }
    }
  }
  float v0 = fmaxf(fmaxf(mx0[0], mx0[1]), fmaxf(mx0[2], mx0[3]));
  float v1 = fmaxf(fmaxf(mx1[0], mx1[1]), fmaxf(mx1[2], mx1[3]));
  v0 = fmaxf(v0, __shfl_xor(v0, 16)); v0 = fmaxf(v0, __shfl_xor(v0, 32));
  v1 = fmaxf(v1, __shfl_xor(v1, 16)); v1 = fmaxf(v1, __shfl_xor(v1, 32));
  if (l < 16) {                          // max(tanh(y+b)) == tanh(max(y)+b)
    const int m = n*NB + b;
    feat[m*OCH + ocb + l]      = (__bf16)tanh_(v0 + cb[ocb + l]);
    feat[m*OCH + ocb + 16 + l] = (__bf16)tanh_(v1 + cb[ocb + 16 + l]);
  }
}

// ---------------------------------------------------------------------------
// K2: gi = feat @ w_ih^T + b_ih (+ b_hh for r,z gates), both directions.
// Output BF16, layout for K3 DMA: gi_t[dir][note][bhalf][j=0..767][b16=0..15]
// ---------------------------------------------------------------------------
__global__ __launch_bounds__(256, 2) void k2_gi(
    const __bf16* __restrict__ feat,
    const float* __restrict__ wihf, const float* __restrict__ bihf, const float* __restrict__ bhhf,
    const float* __restrict__ wihb, const float* __restrict__ bihb, const float* __restrict__ bhhb,
    __bf16* __restrict__ gi_t)
{
  const int bid = blockIdx.x;
  const int mblk = bid & 31, cblk = bid >> 5;     // cblk 0..23
  const int dir = (cblk >= 12) ? 1 : 0;
  const int jb = (cblk - dir*12)*64;
  const float* wih = dir ? wihb : wihf;
  const float* bih = dir ? bihb : bihf;
  const float* bhh = dir ? bhhb : bhhf;
  const int t = threadIdx.x, wv = t >> 6, l = t & 63;
  const int lo = l & 15, hi = l >> 4;
  const int mbase = mblk*64 + wv*16;
  bf16x8 Af[8];
  #pragma unroll
  for (int kf = 0; kf < 8; ++kf)
    Af[kf] = *(const bf16x8*)(feat + (mbase + lo)*HD + kf*32 + hi*8);
  bf16x8 Bf[4][8];
  #pragma unroll
  for (int nt = 0; nt < 4; ++nt) {
    int j = jb + nt*16 + lo;
    #pragma unroll
    for (int kf = 0; kf < 8; ++kf) {
      const float* src = wih + j*HD + kf*32 + hi*8;
      Bf[nt][kf] = pack8(*(const f32x4*)src, *(const f32x4*)(src + 4));
    }
  }
  f32x4 acc[4];
  #pragma unroll
  for (int nt = 0; nt < 4; ++nt) { f32x4 z = {0,0,0,0}; acc[nt] = z; }
  #pragma unroll
  for (int kf = 0; kf < 8; ++kf)
    #pragma unroll
    for (int nt = 0; nt < 4; ++nt)
      acc[nt] = __builtin_amdgcn_mfma_f32_16x16x32_bf16(Af[kf], Bf[nt][kf], acc[nt], 0,0,0);
  #pragma unroll
  for (int nt = 0; nt < 4; ++nt) {
    int j = jb + nt*16 + lo;
    float bias = bih[j] + (j < 512 ? bhh[j] : 0.f);
    #pragma unroll
    for (int r = 0; r < 4; ++r) {
      int m = mbase + hi*4 + r;
      int note = m >> 5, bb = m & 31;
      gi_t[((((long)dir*NN + note)*2 + (bb >> 4))*G3 + j)*16 + (bb & 15)]
          = (__bf16)(acc[nt][r] + bias);
    }
  }
}

// ---------------------------------------------------------------------------
// K3: persistent GRU. grid=4 (dir x batch-half), 16 waves of 1024 threads.
// Wave wv owns hidden col j=wv*16+lo for ALL THREE gates -> register-only
// gate math. Weights: 24 bf16x8 = 96 VGPR/lane.
//
// REGISTER-BUDGET THEORY (R5/R6/R9 post-mortems): the allocator's VGPR
// budget = 512 / (waves-per-EU target), and the target is the max occupancy
// the LDS size permits. R9: LDS=64KB -> 2 blocks/CU -> 8 waves/EU -> 64-reg
// tier -> weights spilled. Fix: (a) pad LDS to 82944B so only 1 block/CU
// fits -> target 4 waves/EU -> 128-reg budget; (b) __launch_bounds__(1024,4)
// pins the same floor; (c) demand trimmed to ~126 (96 weights + 12 acc +
// 4 h + addressing via incremental pointers).
// ---------------------------------------------------------------------------
__global__ __launch_bounds__(1024, 4) void k3_gru(
    const __bf16* __restrict__ gi_t,
    const float* __restrict__ whhf, const float* __restrict__ bhhf,
    const float* __restrict__ whhb, const float* __restrict__ bhhb,
    const float* __restrict__ hid,
    float* __restrict__ out)
{
  const int blk = blockIdx.x;
  const int dir = blk >> 1, mtb = blk & 1;
  const float* whh = dir ? whhb : whhf;
  const float* bhh = dir ? bhhb : bhhf;
  const int t = threadIdx.x, wv = t >> 6, l = t & 63;
  const int lo = l & 15, hi = l >> 4;
  __shared__ __bf16 hb[2][16*256];    // 8 KB each, swizzled 16B chunks
  __shared__ __bf16 gib[2][G3*16];    // 24 KB each: [j][b16] bf16
  __shared__ __bf16 pad_[8704];       // 17 KB occupancy limiter: LDS 82944B
  if ((int)blockIdx.x < 0) pad_[0] = (__bf16)1.f;  // opaque keep-alive

  const int jl = wv*16 + lo;          // this lane's hidden unit
  bf16x8 Bf[3][8];                    // [gate][kf] = 96 VGPR
  #pragma unroll
  for (int g = 0; g < 3; ++g) {
    const int col = g*256 + jl;
    #pragma unroll
    for (int kf = 0; kf < 8; ++kf) {
      const float* src = whh + col*HD + kf*32 + hi*8;
      Bf[g][kf] = pack8(*(const f32x4*)src, *(const f32x4*)(src + 4));
    }
  }
  const float bnh = bhh[512 + jl];

  float h[4];                         // rows m = hi*4+r (in batch-half), col jl
  #pragma unroll
  for (int r = 0; r < 4; ++r)
    h[r] = hid[dir*(NB*HD) + (mtb*16 + hi*4 + r)*HD + jl];
  #pragma unroll
  for (int r = 0; r < 4; ++r) {
    const int row = hi*4 + r;
    *(__bf16*)((char*)&hb[0][0] + row*512 + (((jl >> 3) ^ (row & 7)) << 4) + (jl & 7)*2)
        = (__bf16)h[r];
  }

  // incremental pointers (constant per-step stride, sign = direction)
  const long gstride = (long)(dir ? -1 : 1) * 2 * G3 * 16;   // bf16 elems/note
  const long ostride = (long)(dir ? -1 : 1) * NB * 512;      // f32 elems/note
  // gi prefetch pointer starts at the step-1 note
  const __bf16* gpref = gi_t
      + ((long)(dir*NN + (dir ? 62 : 1))*2 + mtb)*(G3*16) + wv*512 + l*8;
  // out pointer for this lane at step-0 note (rows via +r*512)
  float* outp = out
      + (long)((dir ? 63 : 0)*NB + mtb*16 + hi*4)*512 + dir*HD + jl;

  // prologue: DMA gi for step 0 into gib[0]  (24 KB = 24 wave-instructions)
  {
    const __bf16* gt = gi_t + ((long)(dir*NN + (dir ? 63 : 0))*2 + mtb)*(G3*16);
    gload_lds16(gt + wv*512 + l*8, &gib[0][wv*512]);
    if (wv < 8) gload_lds16(gt + (16 + wv)*512 + l*8, &gib[0][(16 + wv)*512]);
  }
  asm volatile("s_waitcnt vmcnt(0) lgkmcnt(0)\n\ts_barrier" ::: "memory");

  int cur = 0;
  for (int st = 0; st < 64; ++st) {
    // prefetch next step's gi into gib[cur^1] (hidden under this step's MFMA)
    if (st < 63) {
      gload_lds16(gpref, &gib[cur ^ 1][wv*512]);
      if (wv < 8) gload_lds16(gpref + 8192, &gib[cur ^ 1][(16 + wv)*512]);
      gpref += gstride;
    }
    // MFMA: gh for cols {jl, jl+256, jl+512}
    f32x4 acc[3];
    #pragma unroll
    for (int g = 0; g < 3; ++g) { f32x4 z = {0,0,0,0}; acc[g] = z; }
    const char* hbc = (const char*)&hb[cur][0];
    #pragma unroll
    for (int kf = 0; kf < 8; ++kf) {
      const int ch = kf*4 + hi;
      bf16x8 Afr = *(const bf16x8*)(hbc + lo*512 + ((ch ^ (lo & 7)) << 4));
      #pragma unroll
      for (int g = 0; g < 3; ++g)
        acc[g] = __builtin_amdgcn_mfma_f32_16x16x32_bf16(Afr, Bf[g][kf], acc[g], 0,0,0);
    }
    // gates (register-only) + h update
    char* hbn = (char*)&hb[cur ^ 1][0];
    const char* gc = (const char*)&gib[cur][0];
    bf16x4 ur  = *(const bf16x4*)(gc + jl*32 + hi*8);           // gate r
    bf16x4 uz  = *(const bf16x4*)(gc + 8192  + jl*32 + hi*8);   // gate z
    bf16x4 un  = *(const bf16x4*)(gc + 16384 + jl*32 + hi*8);   // gate n
    #pragma unroll
    for (int r = 0; r < 4; ++r) {
      float rr = sigm((float)ur[r] + acc[0][r]);
      float zz = sigm((float)uz[r] + acc[1][r]);
      float nn = tanh_((float)un[r] + rr*(acc[2][r] + bnh));
      float hv = (1.f - zz)*nn + zz*h[r];
      h[r] = hv;
      const int row = hi*4 + r;
      *(__bf16*)(hbn + row*512 + (((jl >> 3) ^ (row & 7)) << 4) + (jl & 7)*2) = (__bf16)hv;
      outp[r*512] = hv;
    }
    outp += ostride;
    // counted drain: the 2 (or 1) prefetch DMAs are the oldest VMEM ops and
    // >=4 newer ops (out-stores) exist -> vmcnt(4) drains DMAs, keeps stores
    // in flight, regardless of any compiler-inserted scratch ops in between.
    asm volatile("s_waitcnt vmcnt(4) lgkmcnt(0)\n\ts_barrier" ::: "memory");
    cur ^= 1;
  }
}

// ---------------------------------------------------------------------------
// K4pre: transpose W_note (d,e) -> Wt (e,d) bf16
// ---------------------------------------------------------------------------
__global__ void k4pre(const float* __restrict__ Wn, __bf16* __restrict__ Wt){
  int idx = blockIdx.x*256 + threadIdx.x;
  int e = idx >> 9, d = idx & 511;
  Wt[e*512 + d] = (__bf16)Wn[d*512 + e];
}

// ---------------------------------------------------------------------------
// K4a: attn[m] = sum_e tanh(out_note[m,:] @ W_note[:,e] + bias[e]) * proj[e]
// ---------------------------------------------------------------------------
__global__ __launch_bounds__(256, 2) void k4a(
    const float* __restrict__ onf, const __bf16* __restrict__ Wt,
    const float* __restrict__ bn, const float* __restrict__ pj,
    float* __restrict__ attn)
{
  const int mbase = blockIdx.x*16;
  const int t = threadIdx.x, wv = t >> 6, l = t & 63;
  bf16x8 Af[16];
  #pragma unroll
  for (int kf = 0; kf < 16; ++kf) {
    const float* src = onf + (mbase + (l & 15))*512 + kf*32 + (l >> 4)*8;
    Af[kf] = pack8(*(const f32x4*)src, *(const f32x4*)(src + 4));
  }
  float aa0=0, aa1=0, aa2=0, aa3=0;
  #pragma unroll 1
  for (int ntl = 0; ntl < 8; ++ntl) {
    const int e = wv*128 + ntl*16 + (l & 15);
    const float be = bn[e], pe = pj[e];
    f32x4 acc = {0,0,0,0};
    #pragma unroll
    for (int kf = 0; kf < 16; ++kf) {
      bf16x8 Bfr = *(const bf16x8*)(Wt + e*512 + kf*32 + (l >> 4)*8);
      acc = __builtin_amdgcn_mfma_f32_16x16x32_bf16(Af[kf], Bfr, acc, 0,0,0);
    }
    aa0 += tanh_(acc[0] + be)*pe;
    aa1 += tanh_(acc[1] + be)*pe;
    aa2 += tanh_(acc[2] + be)*pe;
    aa3 += tanh_(acc[3] + be)*pe;
  }
  #pragma unroll
  for (int msk = 8; msk >= 1; msk >>= 1) {
    aa0 += __shfl_xor(aa0, msk); aa1 += __shfl_xor(aa1, msk);
    aa2 += __shfl_xor(aa2, msk); aa3 += __shfl_xor(aa3, msk);
  }
  __shared__ float part[4][16];
  if ((l & 15) == 0) {
    int rb = (l >> 4)*4;
    part[wv][rb+0]=aa0; part[wv][rb+1]=aa1; part[wv][rb+2]=aa2; part[wv][rb+3]=aa3;
  }
  __syncthreads();
  if (t < 16) attn[mbase + t] = part[0][t] + part[1][t] + part[2][t] + part[3][t];
}

// ---------------------------------------------------------------------------
// K4b: per-batch softmax over notes + attention vector + final linear
// ---------------------------------------------------------------------------
__global__ __launch_bounds__(512) void k4b(
    const float* __restrict__ attn, const float* __restrict__ lw, const float* __restrict__ lb,
    float* __restrict__ out)
{
  const int b = blockIdx.x, t = threadIdx.x;
  __shared__ float wl[64];
  __shared__ float vl[512];
  if (t < 64) {
    float a = attn[t*NB + b];
    float mx = a;
    #pragma unroll
    for (int msk = 32; msk >= 1; msk >>= 1) mx = fmaxf(mx, __shfl_xor(mx, msk));
    float ex = __expf(a - mx);
    float s = ex;
    #pragma unroll
    for (int msk = 32; msk >= 1; msk >>= 1) s += __shfl_xor(s, msk);
    float w = ex / s;
    out[1048576 + b*64 + t] = w;   // note_attn_norm [B,N]
    wl[t] = w;
  }
  __syncthreads();
  {
    float acc = 0.f;
    #pragma unroll 1
    for (int n = 0; n < 64; ++n) acc += wl[n]*out[(n*NB + b)*512 + t];
    out[1050624 + b*512 + t] = acc; // note_attn_vectors [B,2H]
    vl[t] = acc;
  }
  __syncthreads();
  if (t < 128) {
    int c = t >> 6, ln = t & 63;
    float p = 0.f;
    for (int d = ln; d < 512; d += 64) p += vl[d]*lw[c*512 + d];
    #pragma unroll
    for (int msk = 32; msk >= 1; msk >>= 1) p += __shfl_xor(p, msk);
    if (ln == 0) out[1067008 + b*2 + c] = p + lb[c]; // final_map [B,2]
  }
}

// ---------------------------------------------------------------------------
extern "C" void kernel_launch(void* const* d_in, const int* in_sizes, int n_in,
                              void* d_out, int out_size, void* d_ws, size_t ws_size,
                              hipStream_t stream) {
  const int*   mb   = (const int*)d_in[0];
  const float* hid  = (const float*)d_in[1];
  const float* emb  = (const float*)d_in[2];
  const float* cw   = (const float*)d_in[3];
  const float* cb   = (const float*)d_in[4];
  const float* wihf = (const float*)d_in[5];
  const float* whhf = (const float*)d_in[6];
  const float* bihf = (const float*)d_in[7];
  const float* bhhf = (const float*)d_in[8];
  const float* wihb = (const float*)d_in[9];
  const float* whhb = (const float*)d_in[10];
  const float* bihb = (const float*)d_in[11];
  const float* bhhb = (const float*)d_in[12];
  const float* Wn   = (const float*)d_in[13];
  const float* bnote= (const float*)d_in[14];
  const float* pj   = (const float*)d_in[15];
  const float* lw   = (const float*)d_in[16];
  const float* lb   = (const float*)d_in[17];
  float* out = (float*)d_out;
  char* ws = (char*)d_ws;
  // layout (embb overlaps gi_t region: embb dead after k1, gi_t born in k2)
  __bf16* feat = (__bf16*)ws;                       // 1 MB     [2048 x 256]
  __bf16* embb = (__bf16*)(ws + 1048576);           // 12.8 MB  [50000 x 128]
  __bf16* gi_t = (__bf16*)(ws + 1048576);           // 6.29 MB  [2][64][2][768][16] bf16
  float*  attn = (float*)(ws + 13848576);           // 8 KB     [2048]
  __bf16* Wt   = (__bf16*)(ws + 13856768);          // 512 KB   [512 x 512]
  __bf16* cwb  = (__bf16*)(ws + 14380800);          // 192 KB   [256 x 384]

  k0_cvt<<<3173, 256, 0, stream>>>(emb, cw, embb, cwb);
  k1_conv<<<2048, 512, 0, stream>>>(mb, embb, cwb, cb, feat);
  k2_gi<<<768, 256, 0, stream>>>(feat, wihf, bihf, bhhf, wihb, bihb, bhhb, gi_t);
  k4pre<<<1024, 256, 0, stream>>>(Wn, Wt);
  k3_gru<<<4, 1024, 0, stream>>>(gi_t, whhf, bhhf, whhb, bhhb, hid, out);
  k4a<<<128, 256, 0, stream>>>(out, Wt, bnote, pj, attn);
  k4b<<<32, 512, 0, stream>>>(attn, lw, lb, out);
}